// Round 3
// baseline (166.871 us; speedup 1.0000x reference)
//
#include <hip/hip_runtime.h>

// Problem: B=256, T=256 trees, E=64, H=4.
// out[b,t,e] = sum_{j!=t,h} relu(x[b,j,:]·W1[t,j,:,h] + b1[t,j,h]) * W2[t,pos(j)*4+h,e] + b2[t,e]
//
// R3: cache-BW-bound fix. 512 blocks x 512 threads (8 waves).
// Block = 8 trees x 64 batches x 64 j's (jg atomically accumulates).
// XCD swizzle: xcd = tg&7 -> all bg/jg partners co-resident on one XCD (W1/W2/out L2-local).
// Swapped GEMM1 (A=W1,B=x) -> P writes are b64-vectorized; W2b double-buffered (2 barriers/chunk).

namespace {

constexpr int T_ = 256;
constexpr int E_ = 64;
constexpr int K2_ = 1020;           // (T-1)*H
constexpr int JC = 4;               // j's per chunk (K=16 for GEMM2, zero-padded to 32)
constexpr int CHUNKS = 16;          // 64 j's per block / JC

// LDS geometry (u16 units). All planes/rows 16B-aligned; pads chosen from bank audit.
constexpr int W1T_ROW   = 72;              // 64 used + 8 (144B row: A-read at b128 conflict floor)
constexpr int W1T_PLANE = 32 * W1T_ROW + 8;  // 2312 u16 = 4624B, shifts banks by 2/plane
constexpr int PB_PLANE  = 64 * 16 + 8;       // 1032 u16; rows 16 u16 (32B)
constexpr int W2_PLANE  = 64 * 16 + 8;       // 1032 u16

typedef float  f32x4  __attribute__((ext_vector_type(4)));
typedef short  bf16x8 __attribute__((ext_vector_type(8)));
typedef unsigned short u16x4 __attribute__((ext_vector_type(4)));

__device__ inline unsigned short f2b(float f) {
    union { float f; unsigned u; } v; v.f = f;
    unsigned r = v.u + 0x7fffu + ((v.u >> 16) & 1u);   // RNE bf16
    return (unsigned short)(r >> 16);
}

__device__ inline bf16x8 pack8(f32x4 a, f32x4 b) {
    bf16x8 r;
    r[0] = (short)f2b(a[0]); r[1] = (short)f2b(a[1]);
    r[2] = (short)f2b(a[2]); r[3] = (short)f2b(a[3]);
    r[4] = (short)f2b(b[0]); r[5] = (short)f2b(b[1]);
    r[6] = (short)f2b(b[2]); r[7] = (short)f2b(b[3]);
    return r;
}

} // namespace

// out[b,t,e] = b2[t,e]  (accumulation base)
__global__ __launch_bounds__(256) void init_out_kernel(
    const float* __restrict__ b2, float* __restrict__ out)
{
    const int idx = blockIdx.x * 256 + threadIdx.x;    // 1,048,576 f32x4's
    ((f32x4*)out)[idx] = ((const f32x4*)b2)[idx & 4095];
}

// x (f32) -> bf16 workspace
__global__ __launch_bounds__(256) void xcast_kernel(
    const float* __restrict__ x, unsigned short* __restrict__ xb)
{
    const int idx = blockIdx.x * 256 + threadIdx.x;    // 524,288 groups of 8
    f32x4 a = ((const f32x4*)x)[2 * idx];
    f32x4 b = ((const f32x4*)x)[2 * idx + 1];
    ((bf16x8*)xb)[idx] = pack8(a, b);
}

template <bool XBF>
__global__ __launch_bounds__(512, 4) void fused_forest_kernel(
    const void*  __restrict__ xv,  // bf16 [256][256][64] (XBF) or f32
    const float* __restrict__ W1,  // [256][256][64][4]
    const float* __restrict__ b1,  // [256][256][4]
    const float* __restrict__ W2,  // [256][1020][64]
    float* __restrict__ out)       // [256][256][64], pre-initialized to b2
{
    __shared__ __align__(16) unsigned short sW1[4 * W1T_PLANE];     // [jj][ih=i*4+h][e] 18496B
    __shared__ __align__(16) unsigned short sPB[8 * PB_PLANE];      // [i][b_loc][kk]   16512B
    __shared__ __align__(16) unsigned short sW2[2][8 * W2_PLANE];   // dbuf [i][e][kk]  33024B
    __shared__ __align__(16) float sB1[4][32];                      // [jj][ih]           512B

    const int bid = blockIdx.x;
    // XCD-locality swizzle: xcd = tg&7 => each XCD owns 4 tree-groups, all bg, all jg.
    const int xcd = bid & 7;
    const int rr  = bid >> 3;           // 0..63
    const int tgl = rr >> 4;            // 0..3
    const int bg  = (rr >> 2) & 3;      // 0..3
    const int jg  = rr & 3;             // 0..3
    const int tg  = tgl * 8 + xcd;      // 0..31
    const int i0  = tg << 3;            // 8 trees
    const int b0  = bg << 6;            // 64 batches
    const int j0g = jg << 6;            // 64 j's

    const int tid  = threadIdx.x;
    const int w    = tid >> 6;          // wave 0..7
    const int lane = tid & 63;
    const int r16  = lane & 15;
    const int kg   = lane >> 4;         // 0..3
    const int bt   = w & 3;             // GEMM1 batch tile
    const int mh   = w >> 2;            // GEMM1 ih-half (trees mh*4..mh*4+3)

    f32x4 acc[4][4];                    // wave's 64b x 64e tile for tree i0+w
    #pragma unroll
    for (int mt = 0; mt < 4; ++mt)
        #pragma unroll
        for (int nt = 0; nt < 4; ++nt)
            acc[mt][nt] = (f32x4){0.f, 0.f, 0.f, 0.f};

    // ---------------- staging lambda: chunk c -> sW1, sB1, sW2[pb] ----------------
    auto stage = [&](int c, int pb) {
        const int j0 = j0g + c * JC;
        // b1: 128 entries
        if (tid < 128) {
            const int jj = tid >> 5, ih = tid & 31;
            sB1[jj][ih] = b1[((i0 + (ih >> 2)) * T_ + (j0 + jj)) * 4 + (ih & 3)];
        }
        // W1t[jj][i*4+h][e] = bf16(W1[i0+i][j0+jj][e][h]); thread: i=w, jj=kg, e0=r16*4
        {
            const float* src = W1 + (((size_t)(i0 + w) * T_ + (j0 + kg)) * E_) * 4 + r16 * 16;
            f32x4 v0 = *(const f32x4*)(src);
            f32x4 v1 = *(const f32x4*)(src + 4);
            f32x4 v2 = *(const f32x4*)(src + 8);
            f32x4 v3 = *(const f32x4*)(src + 12);   // v[q] = (e = 4*r16+q, h=0..3)
            #pragma unroll
            for (int h = 0; h < 4; ++h) {
                u16x4 pk = (u16x4){f2b(v0[h]), f2b(v1[h]), f2b(v2[h]), f2b(v3[h])};
                *(u16x4*)&sW1[kg * W1T_PLANE + (w * 4 + h) * W1T_ROW + r16 * 4] = pk;
            }
        }
        // W2b[i][e][kk] = bf16(W2[t][pos(j)*4+h][e]); thread: i=w, kk=(lane>>2)&15, e0=lane&3
        {
            const int kk   = (lane >> 2) & 15;
            const int e0   = lane & 3;
            const int tabs = i0 + w;
            const int j    = j0 + (kk >> 2);
            unsigned short* dst = &sW2[pb][w * W2_PLANE + kk];
            if (j == tabs) {
                #pragma unroll
                for (int s = 0; s < 16; ++s) dst[(e0 + 4 * s) * 16] = 0;
            } else {
                const int ksrc = ((j < tabs) ? j : j - 1) * 4 + (kk & 3);
                const float* src = W2 + ((size_t)tabs * K2_ + ksrc) * E_ + e0;
                #pragma unroll
                for (int s = 0; s < 16; ++s)
                    dst[(e0 + 4 * s) * 16] = f2b(src[4 * s]);
            }
        }
    };

    stage(0, 0);
    __syncthreads();

    const int brow = b0 + bt * 16 + r16;   // this thread's GEMM1 batch row

    for (int c = 0; c < CHUNKS; ++c) {
        const int j0 = j0g + c * JC;

        // ---- GEMM1 (swapped): D[m=ih][n=batch] = W1 · x; relu+bias; P -> sPB ----
        #pragma unroll
        for (int jj = 0; jj < JC; ++jj) {
            bf16x8 xa, xc;
            if (XBF) {
                const unsigned short* xr =
                    (const unsigned short*)xv + ((size_t)brow * T_ + (j0 + jj)) * E_;
                xa = *(const bf16x8*)(xr + kg * 8);
                xc = *(const bf16x8*)(xr + 32 + kg * 8);
            } else {
                const float* xr = (const float*)xv + ((size_t)brow * T_ + (j0 + jj)) * E_ + kg * 8;
                xa = pack8(*(const f32x4*)xr, *(const f32x4*)(xr + 4));
                xc = pack8(*(const f32x4*)(xr + 32), *(const f32x4*)(xr + 36));
            }
            const unsigned short* wr = &sW1[jj * W1T_PLANE + (mh * 16 + r16) * W1T_ROW];
            bf16x8 wa = *(const bf16x8*)(wr + kg * 8);
            bf16x8 wc = *(const bf16x8*)(wr + 32 + kg * 8);
            f32x4 cf = (f32x4){0.f, 0.f, 0.f, 0.f};
            cf = __builtin_amdgcn_mfma_f32_16x16x32_bf16(wa, xa, cf, 0, 0, 0);
            cf = __builtin_amdgcn_mfma_f32_16x16x32_bf16(wc, xc, cf, 0, 0, 0);
            // lane holds: batch=brow (n=r16), ih = mh*16 + kg*4 + reg -> i = mh*4+kg, h = reg
            const int i = mh * 4 + kg;
            f32x4 bias = *(const f32x4*)&sB1[jj][i * 4];
            #pragma unroll
            for (int r = 0; r < 4; ++r) {
                float vv = cf[r] + bias[r];
                cf[r] = vv > 0.f ? vv : 0.f;
            }
            unsigned p0 = (unsigned)f2b(cf[0]) | ((unsigned)f2b(cf[1]) << 16);
            unsigned p1 = (unsigned)f2b(cf[2]) | ((unsigned)f2b(cf[3]) << 16);
            uint2 pk; pk.x = p0; pk.y = p1;   // kk = jj*4 + h, h=0..3
            *(uint2*)&sPB[i * PB_PLANE + (bt * 16 + r16) * 16 + jj * 4] = pk;
        }
        __syncthreads();

        // ---- GEMM2: acc += P[tree w] · W2b[tree w]  (M=64,N=64,K=16 in K=32 MFMA) ----
        {
            const bf16x8 z = (bf16x8){0,0,0,0,0,0,0,0};
            const bool lo = (kg < 2);
            bf16x8 a2[4], bb[4];
            #pragma unroll
            for (int mt = 0; mt < 4; ++mt)
                a2[mt] = lo ? *(const bf16x8*)&sPB[w * PB_PLANE + (mt * 16 + r16) * 16 + kg * 8] : z;
            #pragma unroll
            for (int nt = 0; nt < 4; ++nt)
                bb[nt] = lo ? *(const bf16x8*)&sW2[c & 1][w * W2_PLANE + (nt * 16 + r16) * 16 + kg * 8] : z;
            #pragma unroll
            for (int mt = 0; mt < 4; ++mt)
                #pragma unroll
                for (int nt = 0; nt < 4; ++nt)
                    acc[mt][nt] = __builtin_amdgcn_mfma_f32_16x16x32_bf16(
                        a2[mt], bb[nt], acc[mt][nt], 0, 0, 0);
        }

        // ---- stage next chunk (overlaps GEMM2 phase; W2 double-buffered) ----
        if (c + 1 < CHUNKS) stage(c + 1, (c + 1) & 1);
        __syncthreads();
    }

    // ---- epilogue: out[b, i0+w, e] += acc (atomic; out pre-set to b2) ----
    const int tabs = i0 + w;
    #pragma unroll
    for (int mt = 0; mt < 4; ++mt) {
        const int b = b0 + mt * 16 + kg * 4;
        #pragma unroll
        for (int nt = 0; nt < 4; ++nt) {
            const int e = nt * 16 + r16;
            #pragma unroll
            for (int r = 0; r < 4; ++r)
                unsafeAtomicAdd(&out[((size_t)(b + r) * T_ + tabs) * E_ + e],
                                acc[mt][nt][r]);
        }
    }
}

extern "C" void kernel_launch(void* const* d_in, const int* in_sizes, int n_in,
                              void* d_out, int out_size, void* d_ws, size_t ws_size,
                              hipStream_t stream) {
    const float* x  = (const float*)d_in[0];
    const float* W1 = (const float*)d_in[1];
    const float* b1 = (const float*)d_in[2];
    const float* W2 = (const float*)d_in[3];
    const float* b2 = (const float*)d_in[4];
    float* out = (float*)d_out;
    (void)in_sizes; (void)n_in; (void)out_size;

    const size_t xbf_bytes = (size_t)256 * 256 * 64 * 2;   // 8.4 MB
    const bool xbf = ws_size >= xbf_bytes && d_ws != nullptr;

    hipLaunchKernelGGL(init_out_kernel, dim3(4096), dim3(256), 0, stream, b2, out);

    if (xbf) {
        hipLaunchKernelGGL(xcast_kernel, dim3(2048), dim3(256), 0, stream,
                           x, (unsigned short*)d_ws);
        hipLaunchKernelGGL(fused_forest_kernel<true>, dim3(512), dim3(512), 0, stream,
                           (const void*)d_ws, W1, b1, W2, out);
    } else {
        hipLaunchKernelGGL(fused_forest_kernel<false>, dim3(512), dim3(512), 0, stream,
                           (const void*)x, W1, b1, W2, out);
    }
}

// Round 4
// 155.643 us; speedup vs baseline: 1.0721x; 1.0721x over previous
//
#include <hip/hip_runtime.h>

// Problem: B=256, T=256 trees, E=64, H=4.
// out[b,t,e] = sum_{j!=t,h} relu(x[b,j,:]·W1[t,j,:,h] + b1[t,j,h]) * W2[t,pos(j)*4+h,e] + b2[t,e]
//
// R4: fix request-rate bottleneck. x pre-transposed to xT[j][b][e] bf16 so GEMM1
// B-operand loads are lane-contiguous (2KB/instr, full sectors). W2 staging reads
// coalesced (wave covers 4KB contiguous). 512 blocks x 512 threads, 2 blocks/CU.

namespace {

constexpr int T_ = 256;
constexpr int E_ = 64;
constexpr int K2_ = 1020;           // (T-1)*H
constexpr int JC = 4;               // j's per chunk (K=16 for GEMM2, zero-padded to 32)
constexpr int CHUNKS = 16;          // 64 j's per block / JC

// LDS geometry (u16 units); rows 16B-aligned, bank-audited.
constexpr int W1_ROW   = 72;               // 144B rows: quarter-wave b128 2-way (free)
constexpr int W1_PLANE = 32 * W1_ROW + 8;  // 2312 u16 (4624B, 16B-aligned)
constexpr int PB_ROW   = 24;               // 48B rows: 2-way (free)
constexpr int PB_PLANE = 64 * PB_ROW + 8;  // 1544 u16 (3088B)
constexpr int W2_ROW   = 16;               // 32B rows: 4-way on GEMM2 B-reads (minor)
constexpr int W2_PLANE = 64 * W2_ROW + 8;  // 1032 u16 (2064B)

typedef float  f32x4  __attribute__((ext_vector_type(4)));
typedef short  bf16x8 __attribute__((ext_vector_type(8)));
typedef unsigned short u16x4 __attribute__((ext_vector_type(4)));

__device__ inline unsigned short f2b(float f) {
    union { float f; unsigned u; } v; v.f = f;
    unsigned r = v.u + 0x7fffu + ((v.u >> 16) & 1u);   // RNE bf16
    return (unsigned short)(r >> 16);
}

__device__ inline bf16x8 pack8(f32x4 a, f32x4 b) {
    bf16x8 r;
    r[0] = (short)f2b(a[0]); r[1] = (short)f2b(a[1]);
    r[2] = (short)f2b(a[2]); r[3] = (short)f2b(a[3]);
    r[4] = (short)f2b(b[0]); r[5] = (short)f2b(b[1]);
    r[6] = (short)f2b(b[2]); r[7] = (short)f2b(b[3]);
    return r;
}

} // namespace

// out[b,t,e] = b2[t,e]  (accumulation base)
__global__ __launch_bounds__(256) void init_out_kernel(
    const float* __restrict__ b2, float* __restrict__ out)
{
    const int idx = blockIdx.x * 256 + threadIdx.x;    // 1,048,576 f32x4's
    ((f32x4*)out)[idx] = ((const f32x4*)b2)[idx & 4095];
}

// x[b][j][e] f32 -> xT[j][b][e] bf16. Reads fully coalesced (consecutive threads
// read consecutive 64B); writes 64B chunks, full sectors.
__global__ __launch_bounds__(256) void xcast_kernel(
    const float* __restrict__ x, unsigned short* __restrict__ xT)
{
    const int g     = blockIdx.x * 256 + threadIdx.x;   // 262,144
    const int part  = g & 3;                            // 16 e's each
    const int rowid = g >> 2;                           // = b*256 + j
    const int b = rowid >> 8, j = rowid & 255;
    const float* src = x + (size_t)rowid * E_ + part * 16;
    f32x4 v0 = *(const f32x4*)(src);
    f32x4 v1 = *(const f32x4*)(src + 4);
    f32x4 v2 = *(const f32x4*)(src + 8);
    f32x4 v3 = *(const f32x4*)(src + 12);
    unsigned short* dst = xT + ((size_t)j * 256 + b) * E_ + part * 16;
    *(bf16x8*)(dst)     = pack8(v0, v1);
    *(bf16x8*)(dst + 8) = pack8(v2, v3);
}

template <bool XBF>
__global__ __launch_bounds__(512, 4) void fused_forest_kernel(
    const void*  __restrict__ xv,  // bf16 xT[j][b][e] (XBF) or f32 x[b][j][e]
    const float* __restrict__ W1,  // [256][256][64][4]
    const float* __restrict__ b1,  // [256][256][4]
    const float* __restrict__ W2,  // [256][1020][64]
    float* __restrict__ out)       // [256][256][64], pre-initialized to b2
{
    __shared__ __align__(16) unsigned short sW1[4 * W1_PLANE];     // [jj][ih][e]   18496B
    __shared__ __align__(16) unsigned short sPB[8 * PB_PLANE];     // [i][b_loc][kk] 24704B
    __shared__ __align__(16) unsigned short sW2[2][8 * W2_PLANE];  // dbuf [i][e][kk] 33024B
    __shared__ __align__(16) float sB1[4][32];                     // [jj][ih]         512B

    const int bid = blockIdx.x;
    // XCD-locality swizzle: xcd = tg&7 => each XCD owns 4 tree-groups, all bg/jg partners.
    const int xcd = bid & 7;
    const int rr  = bid >> 3;           // 0..63
    const int tgl = rr >> 4;            // 0..3
    const int bg  = (rr >> 2) & 3;      // 0..3
    const int jg  = rr & 3;             // 0..3
    const int tg  = tgl * 8 + xcd;      // 0..31
    const int i0  = tg << 3;            // 8 trees
    const int b0  = bg << 6;            // 64 batches
    const int j0g = jg << 6;            // 64 j's

    const int tid  = threadIdx.x;
    const int w    = tid >> 6;          // wave 0..7
    const int lane = tid & 63;
    const int r16  = lane & 15;
    const int kg   = lane >> 4;         // 0..3
    const int bt   = w & 3;             // GEMM1 batch tile
    const int mh   = w >> 2;            // GEMM1 ih-half

    f32x4 acc[4][4];                    // wave's 64b x 64e tile for tree i0+w
    #pragma unroll
    for (int mt = 0; mt < 4; ++mt)
        #pragma unroll
        for (int nt = 0; nt < 4; ++nt)
            acc[mt][nt] = (f32x4){0.f, 0.f, 0.f, 0.f};

    // ---------------- staging: chunk c -> sW1, sB1, sW2[pb] ----------------
    auto stage = [&](int c, int pb) {
        const int j0 = j0g + c * JC;
        // b1: 128 entries
        if (tid < 128) {
            const int jj = tid >> 5, ih = tid & 31;
            sB1[jj][ih] = b1[((i0 + (ih >> 2)) * T_ + (j0 + jj)) * 4 + (ih & 3)];
        }
        // W1t[jj][i*4+h][e]; thread: i=w, jj=kg, e-block=r16 (64B contiguous read)
        {
            const float* src = W1 + (((size_t)(i0 + w) * T_ + (j0 + kg)) * E_) * 4 + r16 * 16;
            f32x4 v0 = *(const f32x4*)(src);
            f32x4 v1 = *(const f32x4*)(src + 4);
            f32x4 v2 = *(const f32x4*)(src + 8);
            f32x4 v3 = *(const f32x4*)(src + 12);   // v[q] = (e = 4*r16+q, h=0..3)
            #pragma unroll
            for (int h = 0; h < 4; ++h) {
                u16x4 pk = (u16x4){f2b(v0[h]), f2b(v1[h]), f2b(v2[h]), f2b(v3[h])};
                *(u16x4*)&sW1[kg * W1_PLANE + (w * 4 + h) * W1_ROW + r16 * 4] = pk;
            }
        }
        // W2b[i][e][kk]; thread: i=w, kk=lane>>2, e0=(lane&3)*16 -> wave reads 4KB contiguous
        {
            const int kk   = lane >> 2;            // 0..15
            const int e0   = (lane & 3) * 16;
            const int tabs = i0 + w;
            const int j    = j0 + (kk >> 2);
            unsigned short* dst = &sW2[pb][w * W2_PLANE + kk];
            if (j == tabs) {
                #pragma unroll
                for (int q = 0; q < 16; ++q) dst[(e0 + q) * W2_ROW] = 0;
            } else {
                const int ksrc = ((j < tabs) ? j : j - 1) * 4 + (kk & 3);
                const float* src = W2 + ((size_t)tabs * K2_ + ksrc) * E_ + e0;
                f32x4 v0 = *(const f32x4*)(src);
                f32x4 v1 = *(const f32x4*)(src + 4);
                f32x4 v2 = *(const f32x4*)(src + 8);
                f32x4 v3 = *(const f32x4*)(src + 12);
                #pragma unroll
                for (int q = 0; q < 4; ++q) {
                    dst[(e0 + q)      * W2_ROW] = f2b(v0[q]);
                    dst[(e0 + 4 + q)  * W2_ROW] = f2b(v1[q]);
                    dst[(e0 + 8 + q)  * W2_ROW] = f2b(v2[q]);
                    dst[(e0 + 12 + q) * W2_ROW] = f2b(v3[q]);
                }
            }
        }
    };

    stage(0, 0);
    __syncthreads();

    const int brow = b0 + bt * 16 + r16;   // this thread's GEMM1 batch column (n)

    for (int c = 0; c < CHUNKS; ++c) {
        const int j0 = j0g + c * JC;

        // ---- GEMM1 (swapped): D[m=ih][n=batch] = W1 · x; relu+bias; P -> sPB ----
        #pragma unroll
        for (int jj = 0; jj < JC; ++jj) {
            bf16x8 xa, xc;
            if (XBF) {
                // xT[j][b][e]: lanes (r16=b, kg=e-blk) -> 2KB contiguous per instr
                const unsigned short* xr =
                    (const unsigned short*)xv + ((size_t)(j0 + jj) * 256 + brow) * E_;
                xa = *(const bf16x8*)(xr + kg * 8);
                xc = *(const bf16x8*)(xr + 32 + kg * 8);
            } else {
                const float* xr = (const float*)xv + ((size_t)brow * T_ + (j0 + jj)) * E_ + kg * 8;
                xa = pack8(*(const f32x4*)xr, *(const f32x4*)(xr + 4));
                xc = pack8(*(const f32x4*)(xr + 32), *(const f32x4*)(xr + 36));
            }
            const unsigned short* wr = &sW1[jj * W1_PLANE + (mh * 16 + r16) * W1_ROW];
            bf16x8 wa = *(const bf16x8*)(wr + kg * 8);
            bf16x8 wc = *(const bf16x8*)(wr + 32 + kg * 8);
            f32x4 cf = (f32x4){0.f, 0.f, 0.f, 0.f};
            cf = __builtin_amdgcn_mfma_f32_16x16x32_bf16(wa, xa, cf, 0, 0, 0);
            cf = __builtin_amdgcn_mfma_f32_16x16x32_bf16(wc, xc, cf, 0, 0, 0);
            // lane holds: batch=brow (n=r16), ih = mh*16 + kg*4 + reg -> i=mh*4+kg, h=reg
            const int i = mh * 4 + kg;
            f32x4 bias = *(const f32x4*)&sB1[jj][i * 4];
            #pragma unroll
            for (int r = 0; r < 4; ++r) {
                float vv = cf[r] + bias[r];
                cf[r] = vv > 0.f ? vv : 0.f;
            }
            unsigned p0 = (unsigned)f2b(cf[0]) | ((unsigned)f2b(cf[1]) << 16);
            unsigned p1 = (unsigned)f2b(cf[2]) | ((unsigned)f2b(cf[3]) << 16);
            uint2 pk; pk.x = p0; pk.y = p1;   // kk = jj*4 + h
            *(uint2*)&sPB[i * PB_PLANE + (bt * 16 + r16) * PB_ROW + jj * 4] = pk;
        }
        __syncthreads();

        // ---- GEMM2: acc += P[tree w] · W2b[tree w]  (M=64,N=64,K=16 in K=32 MFMA) ----
        {
            const bf16x8 z = (bf16x8){0,0,0,0,0,0,0,0};
            const bool lo = (kg < 2);
            bf16x8 a2[4], bb[4];
            #pragma unroll
            for (int mt = 0; mt < 4; ++mt)
                a2[mt] = lo ? *(const bf16x8*)&sPB[w * PB_PLANE + (mt * 16 + r16) * PB_ROW + kg * 8] : z;
            #pragma unroll
            for (int nt = 0; nt < 4; ++nt)
                bb[nt] = lo ? *(const bf16x8*)&sW2[c & 1][w * W2_PLANE + (nt * 16 + r16) * W2_ROW + kg * 8] : z;
            #pragma unroll
            for (int mt = 0; mt < 4; ++mt)
                #pragma unroll
                for (int nt = 0; nt < 4; ++nt)
                    acc[mt][nt] = __builtin_amdgcn_mfma_f32_16x16x32_bf16(
                        a2[mt], bb[nt], acc[mt][nt], 0, 0, 0);
        }

        // ---- stage next chunk (overlaps GEMM2; W2 double-buffered) ----
        if (c + 1 < CHUNKS) stage(c + 1, (c + 1) & 1);
        __syncthreads();
    }

    // ---- epilogue: out[b, i0+w, e] += acc (atomic; out pre-set to b2) ----
    const int tabs = i0 + w;
    #pragma unroll
    for (int mt = 0; mt < 4; ++mt) {
        const int b = b0 + mt * 16 + kg * 4;
        #pragma unroll
        for (int nt = 0; nt < 4; ++nt) {
            const int e = nt * 16 + r16;
            #pragma unroll
            for (int r = 0; r < 4; ++r)
                unsafeAtomicAdd(&out[((size_t)(b + r) * T_ + tabs) * E_ + e],
                                acc[mt][nt][r]);
        }
    }
}

extern "C" void kernel_launch(void* const* d_in, const int* in_sizes, int n_in,
                              void* d_out, int out_size, void* d_ws, size_t ws_size,
                              hipStream_t stream) {
    const float* x  = (const float*)d_in[0];
    const float* W1 = (const float*)d_in[1];
    const float* b1 = (const float*)d_in[2];
    const float* W2 = (const float*)d_in[3];
    const float* b2 = (const float*)d_in[4];
    float* out = (float*)d_out;
    (void)in_sizes; (void)n_in; (void)out_size;

    const size_t xbf_bytes = (size_t)256 * 256 * 64 * 2;   // 8.4 MB
    const bool xbf = ws_size >= xbf_bytes && d_ws != nullptr;

    hipLaunchKernelGGL(init_out_kernel, dim3(4096), dim3(256), 0, stream, b2, out);

    if (xbf) {
        hipLaunchKernelGGL(xcast_kernel, dim3(1024), dim3(256), 0, stream,
                           x, (unsigned short*)d_ws);
        hipLaunchKernelGGL(fused_forest_kernel<true>, dim3(512), dim3(512), 0, stream,
                           (const void*)d_ws, W1, b1, W2, out);
    } else {
        hipLaunchKernelGGL(fused_forest_kernel<false>, dim3(512), dim3(512), 0, stream,
                           (const void*)x, W1, b1, W2, out);
    }
}